// Round 1
// 8274.631 us; speedup vs baseline: 1.2649x; 1.2649x over previous
//
#include <hip/hip_runtime.h>
#include <math.h>

// HyperLSTM fp32 — round 2: batched GEMMs (input projections + decoder) moved to
// split-bf16 (hi/lo) MFMA: C = Ah*Bh + Ah*Bl + Al*Bh, fp32 accumulate.
// Residual error <= 2^-17 relative — negligible vs current absmax 4.9e-4.
// Recurrent loop (k_rec_gemm/k_gates) intentionally unchanged this round.

#define LDX 1152      // padded feature stride
#define LDG 4608      // padded gate stride (4*1152)
#define TKK 16        // K tile for fp32 rec GEMM

using bf16x8 = __attribute__((ext_vector_type(8))) short;
using f32x4  = __attribute__((ext_vector_type(4))) float;

__device__ inline ushort f32_to_bf16(float f) {  // round-to-nearest-even
    unsigned u = __float_as_uint(f);
    u += 0x7fffu + ((u >> 16) & 1u);
    return (ushort)(u >> 16);
}
__device__ inline float bf16f(ushort h) { return __uint_as_float((unsigned)h << 16); }

// ---------------------------------------------------------------- embed
__global__ __launch_bounds__(256) void k_embed(
    const int* __restrict__ tokens, const float* __restrict__ hnet,
    const float* __restrict__ elem_emb, const float* __restrict__ hnet_emb,
    const float* __restrict__ embS, float* __restrict__ xA)
{
    int r = blockIdx.x;           // 0..4095  (r = t*64 + b)
    int b = r & 63;
    int tok = tokens[r];
    float hv[7];
#pragma unroll
    for (int q = 0; q < 7; ++q) hv[q] = hnet[b * 7 + q];
    for (int j = threadIdx.x; j < LDX; j += 256) {
        float v = 0.f;
        if (j < 400) {
            float sc = 0.f;
#pragma unroll
            for (int q = 0; q < 7; ++q) sc += hv[q] * embS[j * 7 + q];
            v = elem_emb[(long)tok * 400 + j] + sc * hnet_emb[(long)tok * 400 + j];
        }
        xA[(long)r * LDX + j] = v;
    }
}

// zero pad columns (1150,1151) of an x buffer so K-padded GEMMs read zeros
__global__ void k_zero_pads(float* __restrict__ xB)
{
    int r = blockIdx.x * blockDim.x + threadIdx.x;
    if (r < 4096) {
        xB[(long)r * LDX + 1150] = 0.f;
        xB[(long)r * LDX + 1151] = 0.f;
    }
}

// zero cols 400..415 of the final x buffer before the K=416-padded decoder GEMM
__global__ void k_zero_dec(float* __restrict__ x)
{
    int idx = blockIdx.x * 256 + threadIdx.x;   // 4096*16
    int r = idx >> 4, j = idx & 15;
    x[(long)r * LDX + 400 + j] = 0.f;
}

// ---------------------------------------------------------------- hyper scales + bias
__global__ __launch_bounds__(256) void k_scales(
    const float* __restrict__ hnet,
    const float* __restrict__ Si, const float* __restrict__ bei, const float* __restrict__ bhi,
    const float* __restrict__ Sh, const float* __restrict__ beh, const float* __restrict__ bhh,
    int n, float* __restrict__ wsI, float* __restrict__ wsH, float* __restrict__ biasb)
{
    int idx = blockIdx.x * 256 + threadIdx.x;
    if (idx >= 64 * LDG) return;
    int b = idx / LDG, j = idx - b * LDG;
    int n4 = 4 * n;
    float wi = 0.f, wh = 0.f, bi = 0.f;
    if (j < n4) {
        float bsi = 0.f, bsh = 0.f;
#pragma unroll
        for (int q = 0; q < 7; ++q) {
            float h = hnet[b * 7 + q];
            wi  += h * Si[(long)j * 7 + q];
            bsi += h * Si[(long)(n4 + j) * 7 + q];
            wh  += h * Sh[(long)j * 7 + q];
            bsh += h * Sh[(long)(n4 + j) * 7 + q];
        }
        bi = bei[j] + bsi * bhi[j] + beh[j] + bsh * bhh[j];
    }
    wsI[idx] = wi; wsH[idx] = wh; biasb[idx] = bi;
}

// ---------------------------------------------------------------- h/c init (with zero pads)
__global__ void k_init_state(const float* __restrict__ h0, const float* __restrict__ c0,
                             int n, float* __restrict__ h, float* __restrict__ c)
{
    int idx = blockIdx.x * blockDim.x + threadIdx.x;
    if (idx >= 64 * LDX) return;
    int b = idx / LDX, j = idx - b * LDX;
    float hv = 0.f, cv = 0.f;
    if (j < n) { hv = h0[b * n + j]; cv = c0[b * n + j]; }
    h[idx] = hv; c[idx] = cv;
}

// ---------------------------------------------------------------- split-bf16 MFMA GEMM
// C[M=4096 x N] = A[4096 x K] * B[N x K]^T  (+ optional dbias epilogue w/ col mask)
// A: fp32, stride lda, rows always valid, cols zero-padded to Kiters*32.
// B: fp32, stride ldb (= true K), rows clamped to nB-1, k >= ldb reads as 0.
// Tile 128x128, 4 waves (64x64 each), mfma_f32_16x16x32_bf16, K-step 32.
__global__ __launch_bounds__(256) void k_gemm_split(
    const float* __restrict__ A, int lda,
    const float* __restrict__ B, int ldb, int nB,
    float* __restrict__ C, long ldc,
    const float* __restrict__ dbias, int ncols,
    int Kiters)
{
    __shared__ ushort sAh[128][40];   // +8 bf16 pad: row stride 80 B breaks pow2 banks
    __shared__ ushort sAl[128][40];
    __shared__ ushort sBh[128][40];
    __shared__ ushort sBl[128][40];

    const int tid  = threadIdx.x;
    const int m0   = blockIdx.x * 128;
    const int n0   = blockIdx.y * 128;
    const int lane = tid & 63;
    const int wave = tid >> 6;
    const int wm   = (wave >> 1) * 64;
    const int wn   = (wave & 1) * 64;
    const int fr   = lane & 15;           // frag row (A: M-row, B: N-row)
    const int fk   = (lane >> 4) * 8;     // frag k offset

    const int arow = tid >> 3;            // 0..31 (32 rows per staging pass)
    const int ak   = (tid & 7) * 4;       // 0..28

    const float* pA[4];
    const float* pB[4];
#pragma unroll
    for (int p = 0; p < 4; ++p) {
        pA[p] = A + (long)(m0 + p * 32 + arow) * lda;
        int rb = n0 + p * 32 + arow; if (rb > nB - 1) rb = nB - 1;
        pB[p] = B + (long)rb * ldb;
    }

    f32x4 zero = {0.f, 0.f, 0.f, 0.f};
    f32x4 acc[4][4];
#pragma unroll
    for (int i = 0; i < 4; ++i)
#pragma unroll
        for (int j = 0; j < 4; ++j) acc[i][j] = zero;

    float ra[4][4], rb4[4][4];
    // prologue: load k-tile 0
#pragma unroll
    for (int p = 0; p < 4; ++p) {
        *(float4*)&ra[p][0] = *(const float4*)(pA[p] + ak);
        if (ak < ldb)     *(float2*)&rb4[p][0] = *(const float2*)(pB[p] + ak);
        else { rb4[p][0] = 0.f; rb4[p][1] = 0.f; }
        if (ak + 2 < ldb) *(float2*)&rb4[p][2] = *(const float2*)(pB[p] + ak + 2);
        else { rb4[p][2] = 0.f; rb4[p][3] = 0.f; }
    }

    for (int kt = 0; kt < Kiters; ++kt) {
        // ---- convert fp32 -> (hi, lo) bf16 and stage to LDS
#pragma unroll
        for (int p = 0; p < 4; ++p) {
            int row = p * 32 + arow;
            ushort4 ah, al, bh, bl;
            float f, r;
            f = ra[p][0];  ah.x = f32_to_bf16(f); r = f - bf16f(ah.x); al.x = f32_to_bf16(r);
            f = ra[p][1];  ah.y = f32_to_bf16(f); r = f - bf16f(ah.y); al.y = f32_to_bf16(r);
            f = ra[p][2];  ah.z = f32_to_bf16(f); r = f - bf16f(ah.z); al.z = f32_to_bf16(r);
            f = ra[p][3];  ah.w = f32_to_bf16(f); r = f - bf16f(ah.w); al.w = f32_to_bf16(r);
            f = rb4[p][0]; bh.x = f32_to_bf16(f); r = f - bf16f(bh.x); bl.x = f32_to_bf16(r);
            f = rb4[p][1]; bh.y = f32_to_bf16(f); r = f - bf16f(bh.y); bl.y = f32_to_bf16(r);
            f = rb4[p][2]; bh.z = f32_to_bf16(f); r = f - bf16f(bh.z); bl.z = f32_to_bf16(r);
            f = rb4[p][3]; bh.w = f32_to_bf16(f); r = f - bf16f(bh.w); bl.w = f32_to_bf16(r);
            *(ushort4*)&sAh[row][ak] = ah;
            *(ushort4*)&sAl[row][ak] = al;
            *(ushort4*)&sBh[row][ak] = bh;
            *(ushort4*)&sBl[row][ak] = bl;
        }
        __syncthreads();

        // ---- prefetch next k-tile (in flight across the MFMA phase)
        if (kt + 1 < Kiters) {
            int kg = (kt + 1) * 32 + ak;
#pragma unroll
            for (int p = 0; p < 4; ++p) {
                *(float4*)&ra[p][0] = *(const float4*)(pA[p] + kg);
                if (kg < ldb)     *(float2*)&rb4[p][0] = *(const float2*)(pB[p] + kg);
                else { rb4[p][0] = 0.f; rb4[p][1] = 0.f; }
                if (kg + 2 < ldb) *(float2*)&rb4[p][2] = *(const float2*)(pB[p] + kg + 2);
                else { rb4[p][2] = 0.f; rb4[p][3] = 0.f; }
            }
        }

        // ---- MFMA phase: 3 split-combos x 16 frags
        bf16x8 ahf[4], alf[4];
#pragma unroll
        for (int i = 0; i < 4; ++i) {
            ahf[i] = *(const bf16x8*)&sAh[wm + i * 16 + fr][fk];
            alf[i] = *(const bf16x8*)&sAl[wm + i * 16 + fr][fk];
        }
#pragma unroll
        for (int j = 0; j < 4; ++j) {
            bf16x8 bhf = *(const bf16x8*)&sBh[wn + j * 16 + fr][fk];
            bf16x8 blf = *(const bf16x8*)&sBl[wn + j * 16 + fr][fk];
#pragma unroll
            for (int i = 0; i < 4; ++i) {
                acc[i][j] = __builtin_amdgcn_mfma_f32_16x16x32_bf16(ahf[i], bhf, acc[i][j], 0, 0, 0);
                acc[i][j] = __builtin_amdgcn_mfma_f32_16x16x32_bf16(ahf[i], blf, acc[i][j], 0, 0, 0);
                acc[i][j] = __builtin_amdgcn_mfma_f32_16x16x32_bf16(alf[i], bhf, acc[i][j], 0, 0, 0);
            }
        }
        __syncthreads();
    }

    // ---- epilogue: C/D layout col=lane&15, row=(lane>>4)*4+reg
    const int orow = (lane >> 4) * 4;
    const int ocol = lane & 15;
#pragma unroll
    for (int i = 0; i < 4; ++i) {
#pragma unroll
        for (int j = 0; j < 4; ++j) {
            int col = n0 + wn + j * 16 + ocol;
            long rbase = (long)(m0 + wm + i * 16 + orow);
            if (dbias) {
                if (col < ncols) {
                    float db = dbias[col];
#pragma unroll
                    for (int r = 0; r < 4; ++r)
                        C[(rbase + r) * ldc + col] = acc[i][j][r] + db;
                }
            } else {
#pragma unroll
                for (int r = 0; r < 4; ++r)
                    C[(rbase + r) * ldc + col] = acc[i][j][r];
            }
        }
    }
}

// ---------------------------------------------------------------- combine E/H -> preX
// preX[r][jj] = outE[r][jj] + wsI[b][jj]*outH[r][jj] + biasb[b][jj]
__global__ __launch_bounds__(256) void k_combine(
    const float* __restrict__ outE, const float* __restrict__ outH,
    const float* __restrict__ wsI, const float* __restrict__ biasb,
    float* __restrict__ preX)
{
    long i4 = ((long)blockIdx.x * 256 + threadIdx.x) * 4;
    int r  = (int)(i4 / LDG);
    int jj = (int)(i4 - (long)r * LDG);
    int b = r & 63;
    float4 e  = *(const float4*)&outE[i4];
    float4 h  = *(const float4*)&outH[i4];
    float4 wi = *(const float4*)&wsI[(long)b * LDG + jj];
    float4 bi = *(const float4*)&biasb[(long)b * LDG + jj];
    float4 o;
    o.x = e.x + wi.x * h.x + bi.x;
    o.y = e.y + wi.y * h.y + bi.y;
    o.z = e.z + wi.z * h.z + bi.z;
    o.w = e.w + wi.w * h.w + bi.w;
    *(float4*)&preX[i4] = o;
}

// ---------------------------------------------------------------- recurrent partial GEMM (K-split, fp32)
__global__ __launch_bounds__(256) void k_rec_gemm(
    const float* __restrict__ h,
    const float* __restrict__ Be, const float* __restrict__ Bh,
    float* __restrict__ partE, float* __restrict__ partH,
    int kchunk, int ldb, int n4)
{
    __shared__ __align__(16) float sA[TKK][68], sBe[TKK][68], sBh[TKK][68];
    int n0 = blockIdx.x * 64;
    int ks = blockIdx.y;
    int tid = threadIdx.x;
    int tx = tid & 15, ty = tid >> 4;
    float accE[4][4] = {{0.f}}, accH[4][4] = {{0.f}};
    long bmax = (long)n4 * ldb - 1;
    int kbeg = ks * kchunk, kend = kbeg + kchunk;
    for (int k0 = kbeg; k0 < kend; k0 += TKK) {
#pragma unroll
        for (int i = 0; i < 4; ++i) {
            int e = tid + 256 * i;
            int kk = e & 15, mm = e >> 4;
            sA[kk][mm] = h[(long)mm * LDX + k0 + kk];
            int row = n0 + mm; if (row > n4 - 1) row = n4 - 1;
            long bidx = (long)row * ldb + k0 + kk;
            if (bidx > bmax) bidx = bmax;
            sBe[kk][mm] = Be[bidx];
            sBh[kk][mm] = Bh[bidx];
        }
        __syncthreads();
#pragma unroll
        for (int k = 0; k < TKK; ++k) {
            float4 a4 = *(const float4*)&sA[k][ty * 4];
            float4 e4 = *(const float4*)&sBe[k][tx * 4];
            float4 h4 = *(const float4*)&sBh[k][tx * 4];
            float av[4] = {a4.x, a4.y, a4.z, a4.w};
            float ev[4] = {e4.x, e4.y, e4.z, e4.w};
            float hv[4] = {h4.x, h4.y, h4.z, h4.w};
#pragma unroll
            for (int i = 0; i < 4; ++i)
#pragma unroll
                for (int j = 0; j < 4; ++j) {
                    accE[i][j] += av[i] * ev[j];
                    accH[i][j] += av[i] * hv[j];
                }
        }
        __syncthreads();
    }
#pragma unroll
    for (int i = 0; i < 4; ++i) {
        int r = ty * 4 + i;
        int jj0 = n0 + tx * 4;
        float4 oe = make_float4(accE[i][0], accE[i][1], accE[i][2], accE[i][3]);
        float4 oh = make_float4(accH[i][0], accH[i][1], accH[i][2], accH[i][3]);
        *(float4*)&partE[((long)ks * 64 + r) * LDG + jj0] = oe;
        *(float4*)&partH[((long)ks * 64 + r) * LDG + jj0] = oh;
    }
}

// ---------------------------------------------------------------- gates + state update
__global__ __launch_bounds__(256) void k_gates(
    const float* __restrict__ partE, const float* __restrict__ partH, int KS,
    const float* __restrict__ preX, const float* __restrict__ wsH,
    float* __restrict__ c, float* __restrict__ h, float* __restrict__ xout,
    int n, int t)
{
    int idx = blockIdx.x * 256 + threadIdx.x;
    if (idx >= 64 * n) return;
    int b = idx / n, j = idx - b * n;
    float pre[4];
#pragma unroll
    for (int g = 0; g < 4; ++g) {
        int jj = g * n + j;
        float se = 0.f, sh = 0.f;
        for (int ks = 0; ks < KS; ++ks) {
            se += partE[((long)ks * 64 + b) * LDG + jj];
            sh += partH[((long)ks * 64 + b) * LDG + jj];
        }
        pre[g] = preX[((long)(t * 64 + b)) * LDG + jj] + se + wsH[b * LDG + jj] * sh;
    }
    float f  = 1.f / (1.f + expf(-pre[0]));
    float ii = 1.f / (1.f + expf(-pre[1]));
    float o  = 1.f / (1.f + expf(-pre[2]));
    float g_ = tanhf(pre[3]);
    float cv = f * c[b * LDX + j] + ii * g_;
    float hv = o * tanhf(cv);
    c[b * LDX + j] = cv;
    h[b * LDX + j] = hv;
    xout[((long)(t * 64 + b)) * LDX + j] = hv;
}

// ---------------------------------------------------------------- host
extern "C" void kernel_launch(void* const* d_in, const int* in_sizes, int n_in,
                              void* d_out, int out_size, void* d_ws, size_t ws_size,
                              hipStream_t stream)
{
    const int*   tokens   = (const int*)d_in[0];
    const float* hnet     = (const float*)d_in[1];
    const float* elem_emb = (const float*)d_in[2];
    const float* hnet_emb = (const float*)d_in[3];
    const float* embS     = (const float*)d_in[4];
    const float* dec_bias = (const float*)d_in[41];
    float* out = (float*)d_out;

    // scratch carve (all sizes in floats)
    const size_t SZ_X    = (size_t)4096 * LDX;   // 4,718,592
    const size_t SZ_PRE  = (size_t)4096 * LDG;   // 18,874,368
    const size_t SZ_PART = (size_t)8 * 64 * LDG; // 2,359,296
    const size_t SZ_WS64 = (size_t)64 * LDG;     // 294,912
    const size_t SZ_HC   = (size_t)64 * LDX;     // 73,728

    float* ws = (float*)d_ws;
    // smalls + decoder-input buffer MUST be in ws (decoder writes all of d_out)
    float* xB    = ws;
    float* wsI   = xB + SZ_X;
    float* wsH   = wsI + SZ_WS64;
    float* biasb = wsH + SZ_WS64;
    float* hbuf  = biasb + SZ_WS64;
    float* cbuf  = hbuf + SZ_HC;
    size_t small_need = SZ_X + 3 * SZ_WS64 + 2 * SZ_HC;
    size_t big_need   = SZ_X + 3 * SZ_PRE + 2 * SZ_PART;  // xA + preX + outE + outH + parts
    float *xA, *preX, *partE, *partH, *outEb, *outHb;
    if (ws_size / 4 >= small_need + big_need) {
        xA    = cbuf + SZ_HC;
        preX  = xA + SZ_X;
        partE = preX + SZ_PRE;
        partH = partE + SZ_PART;
        outEb = partH + SZ_PART;
        outHb = outEb + SZ_PRE;
    } else {
        // carve the tail of d_out: all of these are dead before the decoder runs
        float* tail = out + (size_t)out_size;
        partH = tail - SZ_PART;
        partE = partH - SZ_PART;
        preX  = partE - SZ_PRE;
        xA    = preX - SZ_X;
        outEb = xA - SZ_PRE;
        outHb = outEb - SZ_PRE;
    }

    k_embed<<<4096, 256, 0, stream>>>(tokens, hnet, elem_emb, hnet_emb, embS, xA);
    k_zero_pads<<<16, 256, 0, stream>>>(xB);

    const int DIN[3] = {400, 1150, 1150};
    const int NN[3]  = {1150, 1150, 400};
    float* xin = xA;
    float* xout = xB;
    for (int l = 0; l < 3; ++l) {
        const float* We_i = (const float*)d_in[5 + 12 * l + 0];
        const float* Wh_i = (const float*)d_in[5 + 12 * l + 1];
        const float* be_i = (const float*)d_in[5 + 12 * l + 2];
        const float* bh_i = (const float*)d_in[5 + 12 * l + 3];
        const float* S_i  = (const float*)d_in[5 + 12 * l + 4];
        const float* We_h = (const float*)d_in[5 + 12 * l + 5];
        const float* Wh_h = (const float*)d_in[5 + 12 * l + 6];
        const float* be_h = (const float*)d_in[5 + 12 * l + 7];
        const float* bh_h = (const float*)d_in[5 + 12 * l + 8];
        const float* S_h  = (const float*)d_in[5 + 12 * l + 9];
        const float* h0   = (const float*)d_in[5 + 12 * l + 10];
        const float* c0   = (const float*)d_in[5 + 12 * l + 11];
        int n = NN[l], din = DIN[l], n4 = 4 * n;
        int Kit_in = (din + 31) / 32;             // 13 or 36
        int ntB    = (n4 + 127) / 128;            // 36 or 13
        int Kpad_rec = (n == 1150) ? 1152 : 400;
        int NtilesR = (n4 + 63) / 64;             // 72 or 25 (fp32 rec path)
        int KS = (n == 1150) ? 8 : 5;
        int kchunk = Kpad_rec / KS;               // 144 or 80

        k_scales<<<(64 * LDG + 255) / 256, 256, 0, stream>>>(
            hnet, S_i, be_i, bh_i, S_h, be_h, bh_h, n, wsI, wsH, biasb);
        k_init_state<<<(64 * LDX + 255) / 256, 256, 0, stream>>>(h0, c0, n, hbuf, cbuf);

        // input projections via split-bf16 MFMA, then combine with hyper-scales+bias
        k_gemm_split<<<dim3(32, ntB), 256, 0, stream>>>(
            xin, LDX, We_i, din, n4, outEb, LDG, nullptr, 0, Kit_in);
        k_gemm_split<<<dim3(32, ntB), 256, 0, stream>>>(
            xin, LDX, Wh_i, din, n4, outHb, LDG, nullptr, 0, Kit_in);
        k_combine<<<(int)((4096L * LDG / 4) / 256), 256, 0, stream>>>(
            outEb, outHb, wsI, biasb, preX);

        for (int t = 0; t < 64; ++t) {
            k_rec_gemm<<<dim3(NtilesR, KS), 256, 0, stream>>>(
                hbuf, We_h, Wh_h, partE, partH, kchunk, n, n4);
            k_gates<<<(64 * n + 255) / 256, 256, 0, stream>>>(
                partE, partH, KS, preX, wsH, cbuf, hbuf, xout, n, t);
        }
        float* tmp = xin; xin = xout; xout = tmp;
    }
    // after 3 swaps xin == xB (in ws): safe while decoder overwrites all of d_out.
    // xB cols 400..1149 hold stale layer-0 output; zero the 400..415 K-pad region.
    k_zero_dec<<<256, 256, 0, stream>>>(xin);
    k_gemm_split<<<dim3(32, 261), 256, 0, stream>>>(
        xin, LDX, elem_emb, 400, 33278, out, 33278, dec_bias, 33278, 13);
}